// Round 3
// baseline (193.227 us; speedup 1.0000x reference)
//
#include <hip/hip_runtime.h>

constexpr int BB   = 2;
constexpr int NN   = 50000;
constexpr int EE   = 600000;
constexpr int CDIM = 128;
constexpr int SEGS = BB * NN;          // 100000

// ws layout:
//   count  u32[SEGS]    @ 0          (400000 B)
//   cursor u32[SEGS]    @ 400000     (400000 B)
//   gcur   u32[1]       @ 800000     (pad to 800256)
//   payload u32[EE]     @ 800256     (2400000 B)

// ---------------------------------------------------------------------------
// hist_k: count[seg]++ per edge (low contention, avg 6 edges/segment).
// ---------------------------------------------------------------------------
__global__ __launch_bounds__(256) void hist_k(
    const int* __restrict__ eidx, unsigned* __restrict__ count)
{
    int e = blockIdx.x * 256 + threadIdx.x;
    if (e >= EE) return;
    int b = eidx[e];
    int t = eidx[EE + e];
    atomicAdd(count + b * NN + t, 1u);
}

// ---------------------------------------------------------------------------
// base_k: assign each segment a contiguous range [base, base+count) in the
// payload array. Order across waves is arbitrary (doesn't matter). One
// global atomic per wave via inclusive shuffle-scan.
// cursor[seg] starts at base; scatter bumps it; gather recovers
// base = cursor_final - count.
// ---------------------------------------------------------------------------
__global__ __launch_bounds__(256) void base_k(
    const unsigned* __restrict__ count, unsigned* __restrict__ cursor,
    unsigned* __restrict__ gcur)
{
    int seg  = blockIdx.x * 256 + threadIdx.x;
    int lane = threadIdx.x & 63;
    unsigned c = (seg < SEGS) ? count[seg] : 0u;
    unsigned incl = c;
    #pragma unroll
    for (int off = 1; off < 64; off <<= 1) {
        unsigned n = __shfl_up(incl, off);
        if (lane >= off) incl += n;
    }
    unsigned total = __shfl(incl, 63);
    unsigned wb = 0;
    if (lane == 63) wb = atomicAdd(gcur, total);
    wb = __shfl(wb, 63);
    if (seg < SEGS) cursor[seg] = wb + incl - c;
}

// ---------------------------------------------------------------------------
// scatter_k: payload[atomicAdd(cursor[seg],1)] = src | (rel<<16).
// ---------------------------------------------------------------------------
__global__ __launch_bounds__(256) void scatter_k(
    const int* __restrict__ eidx, unsigned* __restrict__ cursor,
    unsigned* __restrict__ payload)
{
    int e = blockIdx.x * 256 + threadIdx.x;
    if (e >= EE) return;
    int b = eidx[e];
    int t = eidx[EE + e];
    int s = eidx[2 * EE + e];
    int r = eidx[3 * EE + e];
    unsigned pos = atomicAdd(cursor + b * NN + t, 1u);
    payload[pos] = (unsigned)s | ((unsigned)r << 16);
}

// ---------------------------------------------------------------------------
// gather_k: 32 lanes per segment, 8 segments per block. Payload list is
// contiguous: lane-uniform sequential reads (L1 broadcast, no pointer
// chase). Node-row float4 gathers are independent -> pipelined. Mean is
// fused (divide by count). No atomics.
// ---------------------------------------------------------------------------
__global__ __launch_bounds__(256) void gather_k(
    const float* __restrict__ node, const float* __restrict__ rel,
    const unsigned* __restrict__ count, const unsigned* __restrict__ cursor,
    const unsigned* __restrict__ payload, float* __restrict__ x)
{
    int tid  = threadIdx.x;
    int seg  = blockIdx.x * 8 + (tid >> 5);
    int lane = tid & 31;
    int b    = (seg >= NN) ? 1 : 0;

    unsigned cnt  = count[seg];
    unsigned base = cursor[seg] - cnt;   // cursor ended at base+cnt

    const float* nbase = node + (size_t)b * NN * CDIM + lane * 4;
    const float* rbase = rel + lane * 4;

    float4 acc = {0.f, 0.f, 0.f, 0.f};
    for (unsigned j = 0; j < cnt; ++j) {
        unsigned p = payload[base + j];
        int s = (int)(p & 0xFFFFu);
        int r = (int)(p >> 16);
        float4 hv = *reinterpret_cast<const float4*>(nbase + (size_t)s * CDIM);
        float4 rv = *reinterpret_cast<const float4*>(rbase + r * CDIM);
        acc.x += hv.x - rv.x;
        acc.y += hv.y - rv.y;
        acc.z += hv.z - rv.z;
        acc.w += hv.w - rv.w;
    }

    float inv = 1.f / (float)cnt;   // cnt >= 1 guaranteed (cover edges)
    float4 y = {acc.x * inv, acc.y * inv, acc.z * inv, acc.w * inv};
    *reinterpret_cast<float4*>(x + (size_t)seg * CDIM + lane * 4) = y;
}

// ---------------------------------------------------------------------------
// finish_k (in-place): out[row,:] = x[row,:] @ W.T
// 512 threads, 80 rows/block (1250 blocks, exact), 5x4 register tile.
// 64 KB LDS -> 2 blocks/CU -> 16 waves/CU (50% occupancy).
// Wt swizzle: Wt[d*128 + (o ^ ((d&7)<<2))] -- compute reads conflict-free.
// ---------------------------------------------------------------------------
__global__ __launch_bounds__(512) void finish_k(
    const float* __restrict__ W, float* __restrict__ out)
{
    __shared__ float Wt[CDIM * CDIM];  // 64 KB
    const int tid = threadIdx.x;

    #pragma unroll
    for (int i = 0; i < 32; ++i) {
        int idx = tid + i * 512;
        int o = idx >> 7, d = idx & 127;
        Wt[d * 128 + (o ^ ((d & 7) << 2))] = W[idx];
    }
    __syncthreads();

    const int rowbase = blockIdx.x * 80;
    const int ct = tid & 31;           // output cols ct*4 .. ct*4+3
    const int rt = tid >> 5;           // rows rowbase + rt*5 + 0..4

    float acc[5][4];
    #pragma unroll
    for (int j = 0; j < 5; ++j)
        #pragma unroll
        for (int k = 0; k < 4; ++k) acc[j][k] = 0.f;

    const float* xrow[5];
    #pragma unroll
    for (int j = 0; j < 5; ++j)
        xrow[j] = out + (size_t)(rowbase + rt * 5 + j) * CDIM;

    for (int d = 0; d < CDIM; d += 4) {
        float4 xv[5];
        #pragma unroll
        for (int j = 0; j < 5; ++j)
            xv[j] = *reinterpret_cast<const float4*>(xrow[j] + d);
        #pragma unroll
        for (int dd = 0; dd < 4; ++dd) {
            int dcur = d + dd;
            const float4 w4 = *reinterpret_cast<const float4*>(
                &Wt[dcur * 128 + ((ct * 4) ^ ((dcur & 7) << 2))]);
            #pragma unroll
            for (int j = 0; j < 5; ++j) {
                float xs = dd == 0 ? xv[j].x : dd == 1 ? xv[j].y
                         : dd == 2 ? xv[j].z : xv[j].w;
                acc[j][0] += xs * w4.x;
                acc[j][1] += xs * w4.y;
                acc[j][2] += xs * w4.z;
                acc[j][3] += xs * w4.w;
            }
        }
    }

    __syncthreads();  // all x reads done before in-place overwrite

    #pragma unroll
    for (int j = 0; j < 5; ++j) {
        float4 y = {acc[j][0], acc[j][1], acc[j][2], acc[j][3]};
        *reinterpret_cast<float4*>(
            out + (size_t)(rowbase + rt * 5 + j) * CDIM + ct * 4) = y;
    }
}

extern "C" void kernel_launch(void* const* d_in, const int* in_sizes, int n_in,
                              void* d_out, int out_size, void* d_ws, size_t ws_size,
                              hipStream_t stream) {
    const float* node = (const float*)d_in[0];
    const int*   eidx = (const int*)d_in[1];
    const float* rel  = (const float*)d_in[2];
    const float* W    = (const float*)d_in[3];
    float* out = (float*)d_out;

    unsigned* count   = (unsigned*)d_ws;
    unsigned* cursor  = (unsigned*)((char*)d_ws + 400000);
    unsigned* gcur    = (unsigned*)((char*)d_ws + 800000);
    unsigned* payload = (unsigned*)((char*)d_ws + 800256);

    hipMemsetAsync(count, 0, 400000, stream);
    hipMemsetAsync(gcur, 0, 256, stream);

    hist_k   <<<(EE + 255) / 256, 256, 0, stream>>>(eidx, count);
    base_k   <<<(SEGS + 255) / 256, 256, 0, stream>>>(count, cursor, gcur);
    scatter_k<<<(EE + 255) / 256, 256, 0, stream>>>(eidx, cursor, payload);
    gather_k <<<SEGS / 8, 256, 0, stream>>>(node, rel, count, cursor, payload, out);
    finish_k <<<SEGS / 80, 512, 0, stream>>>(W, out);
}

// Round 4
// 111.827 us; speedup vs baseline: 1.7279x; 1.7279x over previous
//
#include <hip/hip_runtime.h>

constexpr int BB   = 2;
constexpr int NN   = 50000;
constexpr int EE   = 600000;
constexpr int CDIM = 128;
constexpr int SEGS = BB * NN;   // 100000
constexpr int CAP  = 32;        // max degree = 1 + Poisson(5); P(>=32) ~ 1e-10

typedef __attribute__((ext_vector_type(8))) short bf16x8;
typedef __attribute__((ext_vector_type(4))) float f32x4;

__device__ __forceinline__ unsigned short f2bf(float f) {
    unsigned u = __builtin_bit_cast(unsigned, f);
    return (unsigned short)((u + 0x7FFFu + ((u >> 16) & 1u)) >> 16);  // RNE
}

// ---------------------------------------------------------------------------
// binscatter_k: one pass. slot = count[seg]++; payload[seg*CAP+slot] = s|r<<16.
// ---------------------------------------------------------------------------
__global__ __launch_bounds__(256) void binscatter_k(
    const int* __restrict__ eidx, unsigned* __restrict__ count,
    unsigned* __restrict__ payload)
{
    int e = blockIdx.x * 256 + threadIdx.x;
    if (e >= EE) return;
    int b = eidx[e];
    int t = eidx[EE + e];
    int s = eidx[2 * EE + e];
    int r = eidx[3 * EE + e];
    int seg = b * NN + t;
    unsigned slot = atomicAdd(count + seg, 1u);
    if (slot < CAP) payload[(size_t)seg * CAP + slot] = (unsigned)s | ((unsigned)r << 16);
}

// ---------------------------------------------------------------------------
// gather_k: ONE 64-lane wave per segment. Lane layout: lane&31 = d-offset
// (float4), lane>>5 = edge-parity half. Payload row (<=32 slots) preloaded
// into a register, distributed via __shfl -- no per-edge payload load.
// Halves combined with __shfl_xor(32). Mean fused. Writes x (f32) to d_out.
// ---------------------------------------------------------------------------
__global__ __launch_bounds__(256) void gather_k(
    const float* __restrict__ node, const float* __restrict__ rel,
    const unsigned* __restrict__ count, const unsigned* __restrict__ payload,
    float* __restrict__ x)
{
    int tid  = threadIdx.x;
    int seg  = blockIdx.x * 4 + (tid >> 6);
    int l    = tid & 63;
    int lane = l & 31;
    int half = l >> 5;
    int b    = (seg >= NN) ? 1 : 0;

    unsigned cnt = count[seg];
    if (cnt > CAP) cnt = CAP;
    unsigned pv = payload[(size_t)seg * CAP + lane];  // slot `lane` (both halves)

    const float* nbase = node + (size_t)b * NN * CDIM + lane * 4;
    const float* rbase = rel + lane * 4;

    float4 acc = {0.f, 0.f, 0.f, 0.f};
    for (unsigned j = (unsigned)half; j < cnt; j += 2) {
        unsigned p = __shfl(pv, (int)j, 32);
        int s = (int)(p & 0xFFFFu);
        int r = (int)(p >> 16);
        float4 hv = *reinterpret_cast<const float4*>(nbase + (size_t)s * CDIM);
        float4 rv = *reinterpret_cast<const float4*>(rbase + r * CDIM);
        acc.x += hv.x - rv.x;
        acc.y += hv.y - rv.y;
        acc.z += hv.z - rv.z;
        acc.w += hv.w - rv.w;
    }

    // combine odd/even halves across the 32-lane boundary
    acc.x += __shfl_xor(acc.x, 32);
    acc.y += __shfl_xor(acc.y, 32);
    acc.z += __shfl_xor(acc.z, 32);
    acc.w += __shfl_xor(acc.w, 32);

    if (half == 0) {
        float inv = 1.f / (float)cnt;  // cnt >= 1 (cover edges)
        float4 y = {acc.x * inv, acc.y * inv, acc.z * inv, acc.w * inv};
        *reinterpret_cast<float4*>(x + (size_t)seg * CDIM + lane * 4) = y;
    }
}

// ---------------------------------------------------------------------------
// finish_k (in-place, bf16 MFMA): out[m,:] = x[m,:] @ W.T
// W -> bf16 in LDS (32 KB), XOR-swizzled 16B granules: byte ^= (o&7)<<4.
// Block = 256 thr (4 waves); wave w owns M-tile (16 rows) x full N=128.
// mfma_f32_16x16x32_bf16: A lane(row=l&15, k=(l>>4)*8+j), B lane(col=l&15,
// k=(l>>4)*8+j), C/D (col=l&15, row=(l>>4)*4+reg)  [guide §3, m89-verified C/D].
// A-frags read f32 x from global and convert; in-place safe: wave reads only
// its own 16 rows, all loads precede all stores in program order.
// ---------------------------------------------------------------------------
__global__ __launch_bounds__(256) void finish_k(
    const float* __restrict__ W, float* out)
{
    __shared__ unsigned short Wb[CDIM * CDIM];  // 32 KB, swizzled bf16
    const int tid = threadIdx.x;

    // stage W -> bf16 LDS. thread t: row o = t>>1, half dh = (t&1)*64.
    {
        int o  = tid >> 1;
        int dh = (tid & 1) * 64;
        const float* wr = W + o * CDIM + dh;
        char* basep = (char*)Wb;
        #pragma unroll
        for (int c = 0; c < 8; ++c) {
            float4 w0 = *reinterpret_cast<const float4*>(wr + c * 8);
            float4 w1 = *reinterpret_cast<const float4*>(wr + c * 8 + 4);
            uint4 pk;
            pk.x = (unsigned)f2bf(w0.x) | ((unsigned)f2bf(w0.y) << 16);
            pk.y = (unsigned)f2bf(w0.z) | ((unsigned)f2bf(w0.w) << 16);
            pk.z = (unsigned)f2bf(w1.x) | ((unsigned)f2bf(w1.y) << 16);
            pk.w = (unsigned)f2bf(w1.z) | ((unsigned)f2bf(w1.w) << 16);
            int off = (o * 256 + (dh + c * 8) * 2) ^ ((o & 7) << 4);
            *reinterpret_cast<uint4*>(basep + off) = pk;
        }
    }
    __syncthreads();

    const int wav = tid >> 6;
    const int l   = tid & 63;
    const int mtile = blockIdx.x * 4 + wav;
    if (mtile >= SEGS / 16) return;   // 6250 tiles; last block partial

    const int c16 = l & 15;
    const int q   = l >> 4;

    // A fragments: row = mtile*16 + c16, k = kstep*32 + q*8 + j
    bf16x8 afr[4];
    const float* xr = out + (size_t)(mtile * 16 + c16) * CDIM + q * 8;
    #pragma unroll
    for (int k = 0; k < 4; ++k) {
        float4 x0 = *reinterpret_cast<const float4*>(xr + k * 32);
        float4 x1 = *reinterpret_cast<const float4*>(xr + k * 32 + 4);
        bf16x8 a;
        a[0] = (short)f2bf(x0.x); a[1] = (short)f2bf(x0.y);
        a[2] = (short)f2bf(x0.z); a[3] = (short)f2bf(x0.w);
        a[4] = (short)f2bf(x1.x); a[5] = (short)f2bf(x1.y);
        a[6] = (short)f2bf(x1.z); a[7] = (short)f2bf(x1.w);
        afr[k] = a;
    }

    f32x4 acc[8];
    #pragma unroll
    for (int n = 0; n < 8; ++n) acc[n] = (f32x4){0.f, 0.f, 0.f, 0.f};

    const char* basep = (const char*)Wb;
    #pragma unroll
    for (int n = 0; n < 8; ++n) {
        int o = n * 16 + c16;  // B col
        #pragma unroll
        for (int k = 0; k < 4; ++k) {
            int off = (o * 256 + k * 64 + q * 16) ^ ((o & 7) << 4);
            bf16x8 bfr = *reinterpret_cast<const bf16x8*>(basep + off);
            acc[n] = __builtin_amdgcn_mfma_f32_16x16x32_bf16(afr[k], bfr, acc[n], 0, 0, 0);
        }
    }

    // store: row = mtile*16 + q*4 + j, col = n*16 + c16
    #pragma unroll
    for (int n = 0; n < 8; ++n) {
        #pragma unroll
        for (int j = 0; j < 4; ++j) {
            out[(size_t)(mtile * 16 + q * 4 + j) * CDIM + n * 16 + c16] = acc[n][j];
        }
    }
}

extern "C" void kernel_launch(void* const* d_in, const int* in_sizes, int n_in,
                              void* d_out, int out_size, void* d_ws, size_t ws_size,
                              hipStream_t stream) {
    const float* node = (const float*)d_in[0];
    const int*   eidx = (const int*)d_in[1];
    const float* rel  = (const float*)d_in[2];
    const float* W    = (const float*)d_in[3];
    float* out = (float*)d_out;

    // ws: count u32[SEGS] @ 0 (400000 B), payload u32[SEGS*CAP] @ 400000 (12.8 MB)
    unsigned* count   = (unsigned*)d_ws;
    unsigned* payload = (unsigned*)((char*)d_ws + 400000);

    hipMemsetAsync(count, 0, (size_t)SEGS * sizeof(unsigned), stream);

    binscatter_k<<<(EE + 255) / 256, 256, 0, stream>>>(eidx, count, payload);
    gather_k    <<<SEGS / 4, 256, 0, stream>>>(node, rel, count, payload, out);
    finish_k    <<<(SEGS / 16 + 3) / 4, 256, 0, stream>>>(W, out);
}

// Round 5
// 110.403 us; speedup vs baseline: 1.7502x; 1.0129x over previous
//
#include <hip/hip_runtime.h>

constexpr int BB   = 2;
constexpr int NN   = 50000;
constexpr int EE   = 600000;
constexpr int CDIM = 128;
constexpr int SEGS = BB * NN;   // 100000
constexpr int CAP  = 32;        // max degree = 1 + Poisson(5); P(>=32) ~ 1e-10
constexpr int EBLK = (EE + 255) / 256;  // 2344 edge blocks in binscatter

typedef __attribute__((ext_vector_type(8))) short bf16x8;
typedef __attribute__((ext_vector_type(4))) float f32x4;

__device__ __forceinline__ unsigned short f2bf(float f) {
    unsigned u = __builtin_bit_cast(unsigned, f);
    return (unsigned short)((u + 0x7FFFu + ((u >> 16) & 1u)) >> 16);  // RNE
}

// ---------------------------------------------------------------------------
// binscatter_k: blocks [0, EBLK) bin edges:
//   slot = count[seg]++; payload[seg*CAP+slot] = src | (rel<<16)
// block EBLK converts W (f32 [128][128], row = out col) to bf16 in
// MFMA-B-fragment-linear layout: 32 frags (n*4+ks) x 64 lanes x 16B, where
// lane l of frag (n,ks) holds W[n*16+(l&15)][ks*32+(l>>4)*8 + j], j=0..7.
// ---------------------------------------------------------------------------
__global__ __launch_bounds__(256) void binscatter_k(
    const int* __restrict__ eidx, unsigned* __restrict__ count,
    unsigned* __restrict__ payload, const float* __restrict__ W,
    unsigned* __restrict__ Wbf)
{
    if (blockIdx.x == EBLK) {
        int t = threadIdx.x;
        #pragma unroll
        for (int i = 0; i < 8; ++i) {
            int u = t * 8 + i;          // 16B unit index, 0..2047
            int l = u & 63, f = u >> 6; // f = n*4 + ks
            int c16 = l & 15, q = l >> 4;
            int col = (f >> 2) * 16 + c16;
            int kb  = (f & 3) * 32 + q * 8;
            const float* wp = W + col * CDIM + kb;
            float4 w0 = *reinterpret_cast<const float4*>(wp);
            float4 w1 = *reinterpret_cast<const float4*>(wp + 4);
            uint4 pk;
            pk.x = (unsigned)f2bf(w0.x) | ((unsigned)f2bf(w0.y) << 16);
            pk.y = (unsigned)f2bf(w0.z) | ((unsigned)f2bf(w0.w) << 16);
            pk.z = (unsigned)f2bf(w1.x) | ((unsigned)f2bf(w1.y) << 16);
            pk.w = (unsigned)f2bf(w1.z) | ((unsigned)f2bf(w1.w) << 16);
            reinterpret_cast<uint4*>(Wbf)[u] = pk;
        }
        return;
    }
    int e = blockIdx.x * 256 + threadIdx.x;
    if (e >= EE) return;
    int b = eidx[e];
    int t = eidx[EE + e];
    int s = eidx[2 * EE + e];
    int r = eidx[3 * EE + e];
    int seg = b * NN + t;
    unsigned slot = atomicAdd(count + seg, 1u);
    if (slot < CAP) payload[(size_t)seg * CAP + slot] = (unsigned)s | ((unsigned)r << 16);
}

// ---------------------------------------------------------------------------
// fused_k: block = 256 thr (4 waves) handles 16 segments = one 16x128 tile.
// Phase 1 (gather): wave w owns segments blockIdx*16 + w*4 .. +3. Lane
// (q=l>>4, c=l&15): quarter q processes edges q, q+4, ... ; chunk of 8 edges
// issues 8 independent 256B half-row load pairs (clamped index + 0/1 weight,
// no branches -> loads batch before waitcnt). Cross-quarter combine via
// shfl_xor(16/32); mean fused; row -> LDS as bf16, XOR-swizzled.
// Phase 2 (MFMA): A-frags from LDS x-tile, B-frags from frag-linear W LDS
// (staged as a 32KB memcpy). Wave w computes cols w*32..w*32+31.
// ---------------------------------------------------------------------------
__global__ __launch_bounds__(256) void fused_k(
    const float* __restrict__ node, const float* __restrict__ rel,
    const unsigned* __restrict__ count, const unsigned* __restrict__ payload,
    const unsigned* __restrict__ Wbf, float* __restrict__ out)
{
    __shared__ __align__(16) unsigned short Wl[32 * 64 * 8];  // 32 KB frag-linear
    __shared__ __align__(16) unsigned short Xl[16 * CDIM];    // 4 KB swizzled

    const int tid = threadIdx.x;

    // stage W: pure 32 KB copy, 128 B/thread
    {
        const uint4* src = reinterpret_cast<const uint4*>(Wbf);
        uint4* dst = reinterpret_cast<uint4*>(Wl);
        #pragma unroll
        for (int i = 0; i < 8; ++i) dst[tid * 8 + i] = src[tid * 8 + i];
    }

    const int wav = tid >> 6;
    const int l   = tid & 63;
    const int q   = l >> 4;
    const int c   = l & 15;

    const int seg0 = blockIdx.x * 16 + wav * 4;

    #pragma unroll
    for (int si = 0; si < 4; ++si) {
        int seg = seg0 + si;
        int b   = (seg >= NN) ? 1 : 0;
        unsigned cnt = count[seg];
        if (cnt > CAP) cnt = CAP;
        unsigned pv = payload[(size_t)seg * CAP + (l & 31)];

        const float* nb = node + (size_t)b * NN * CDIM + c * 8;
        const float* rb = rel + c * 8;

        float acc[8];
        #pragma unroll
        for (int i = 0; i < 8; ++i) acc[i] = 0.f;

        for (unsigned base = 0; base < cnt; base += 8) {
            unsigned j0 = base + q, j1 = base + 4 + q;
            unsigned jc0 = (j0 < cnt) ? j0 : (cnt - 1);
            unsigned jc1 = (j1 < cnt) ? j1 : (cnt - 1);
            float w0 = (j0 < cnt) ? 1.f : 0.f;
            float w1 = (j1 < cnt) ? 1.f : 0.f;
            unsigned p0 = __shfl(pv, (int)jc0, 32);
            unsigned p1 = __shfl(pv, (int)jc1, 32);
            int s0 = (int)(p0 & 0xFFFFu), r0 = (int)(p0 >> 16);
            int s1 = (int)(p1 & 0xFFFFu), r1 = (int)(p1 >> 16);
            const float* h0 = nb + (size_t)s0 * CDIM;
            const float* h1 = nb + (size_t)s1 * CDIM;
            float4 h0a = *reinterpret_cast<const float4*>(h0);
            float4 h0b = *reinterpret_cast<const float4*>(h0 + 4);
            float4 h1a = *reinterpret_cast<const float4*>(h1);
            float4 h1b = *reinterpret_cast<const float4*>(h1 + 4);
            float4 r0a = *reinterpret_cast<const float4*>(rb + r0 * CDIM);
            float4 r0b = *reinterpret_cast<const float4*>(rb + r0 * CDIM + 4);
            float4 r1a = *reinterpret_cast<const float4*>(rb + r1 * CDIM);
            float4 r1b = *reinterpret_cast<const float4*>(rb + r1 * CDIM + 4);
            acc[0] = fmaf(w0, h0a.x - r0a.x, acc[0]);
            acc[1] = fmaf(w0, h0a.y - r0a.y, acc[1]);
            acc[2] = fmaf(w0, h0a.z - r0a.z, acc[2]);
            acc[3] = fmaf(w0, h0a.w - r0a.w, acc[3]);
            acc[4] = fmaf(w0, h0b.x - r0b.x, acc[4]);
            acc[5] = fmaf(w0, h0b.y - r0b.y, acc[5]);
            acc[6] = fmaf(w0, h0b.z - r0b.z, acc[6]);
            acc[7] = fmaf(w0, h0b.w - r0b.w, acc[7]);
            acc[0] = fmaf(w1, h1a.x - r1a.x, acc[0]);
            acc[1] = fmaf(w1, h1a.y - r1a.y, acc[1]);
            acc[2] = fmaf(w1, h1a.z - r1a.z, acc[2]);
            acc[3] = fmaf(w1, h1a.w - r1a.w, acc[3]);
            acc[4] = fmaf(w1, h1b.x - r1b.x, acc[4]);
            acc[5] = fmaf(w1, h1b.y - r1b.y, acc[5]);
            acc[6] = fmaf(w1, h1b.z - r1b.z, acc[6]);
            acc[7] = fmaf(w1, h1b.w - r1b.w, acc[7]);
        }

        // combine quarters: all lanes end with the full sum
        #pragma unroll
        for (int i = 0; i < 8; ++i) {
            acc[i] += __shfl_xor(acc[i], 16);
            acc[i] += __shfl_xor(acc[i], 32);
        }

        if (q == 0) {
            float inv = 1.f / (float)cnt;  // cnt >= 1 (cover edges)
            int row = wav * 4 + si;
            uint4 pk;
            pk.x = (unsigned)f2bf(acc[0] * inv) | ((unsigned)f2bf(acc[1] * inv) << 16);
            pk.y = (unsigned)f2bf(acc[2] * inv) | ((unsigned)f2bf(acc[3] * inv) << 16);
            pk.z = (unsigned)f2bf(acc[4] * inv) | ((unsigned)f2bf(acc[5] * inv) << 16);
            pk.w = (unsigned)f2bf(acc[6] * inv) | ((unsigned)f2bf(acc[7] * inv) << 16);
            int off = (row * 256 + c * 16) ^ ((row & 7) << 4);
            *reinterpret_cast<uint4*>((char*)Xl + off) = pk;
        }
    }

    __syncthreads();  // x-tile + W staged

    // A-frags: lane row = c, k-chunk q; 4 k-steps
    bf16x8 afr[4];
    #pragma unroll
    for (int ks = 0; ks < 4; ++ks) {
        int off = (c * 256 + ks * 64 + q * 16) ^ ((c & 7) << 4);
        afr[ks] = *reinterpret_cast<const bf16x8*>((const char*)Xl + off);
    }

    f32x4 accv[2];
    accv[0] = (f32x4){0.f, 0.f, 0.f, 0.f};
    accv[1] = (f32x4){0.f, 0.f, 0.f, 0.f};
    #pragma unroll
    for (int n2 = 0; n2 < 2; ++n2) {
        int n = wav * 2 + n2;
        #pragma unroll
        for (int ks = 0; ks < 4; ++ks) {
            bf16x8 bfr = *reinterpret_cast<const bf16x8*>(
                (const char*)Wl + ((n * 4 + ks) * 64 + l) * 16);
            accv[n2] = __builtin_amdgcn_mfma_f32_16x16x32_bf16(afr[ks], bfr, accv[n2], 0, 0, 0);
        }
    }

    // store: row = blk*16 + q*4 + j, col = n*16 + c  [C/D: col=l&15, row=(l>>4)*4+reg]
    size_t rowbase = (size_t)blockIdx.x * 16;
    #pragma unroll
    for (int n2 = 0; n2 < 2; ++n2) {
        int n = wav * 2 + n2;
        #pragma unroll
        for (int j = 0; j < 4; ++j) {
            out[(rowbase + q * 4 + j) * CDIM + n * 16 + c] = accv[n2][j];
        }
    }
}

extern "C" void kernel_launch(void* const* d_in, const int* in_sizes, int n_in,
                              void* d_out, int out_size, void* d_ws, size_t ws_size,
                              hipStream_t stream) {
    const float* node = (const float*)d_in[0];
    const int*   eidx = (const int*)d_in[1];
    const float* rel  = (const float*)d_in[2];
    const float* W    = (const float*)d_in[3];
    float* out = (float*)d_out;

    // ws: count u32[SEGS] @0 (400000 B); payload u32[SEGS*CAP] @400000 (12.8 MB);
    //     Wbf (32 KB bf16 frag-linear) @13200000
    unsigned* count   = (unsigned*)d_ws;
    unsigned* payload = (unsigned*)((char*)d_ws + 400000);
    unsigned* Wbf     = (unsigned*)((char*)d_ws + 13200000);

    hipMemsetAsync(count, 0, (size_t)SEGS * sizeof(unsigned), stream);

    binscatter_k<<<EBLK + 1, 256, 0, stream>>>(eidx, count, payload, W, Wbf);
    fused_k<<<SEGS / 16, 256, 0, stream>>>(node, rel, count, payload, Wbf, out);
}

// Round 6
// 90.481 us; speedup vs baseline: 2.1355x; 1.2202x over previous
//
#include <hip/hip_runtime.h>

constexpr int BB   = 2;
constexpr int NN   = 50000;
constexpr int EE   = 600000;
constexpr int CDIM = 128;
constexpr int SEGS = BB * NN;   // 100000
constexpr int CAP  = 32;        // max degree = 1 + Poisson(5); P(>=32) ~ 1e-10
constexpr int EBLK = (EE + 255) / 256;  // edge blocks in binscatter

typedef __attribute__((ext_vector_type(8))) short bf16x8;
typedef __attribute__((ext_vector_type(4))) float f32x4;

__device__ __forceinline__ unsigned short f2bf(float f) {
    unsigned u = __builtin_bit_cast(unsigned, f);
    return (unsigned short)((u + 0x7FFFu + ((u >> 16) & 1u)) >> 16);  // RNE
}

// ---------------------------------------------------------------------------
// binscatter_k: blocks [0, EBLK) bin edges:
//   slot = count[seg]++; payload[seg*CAP+slot] = src | (rel<<16)
// block EBLK converts W (f32 [128][128], row = out col) to bf16 in
// MFMA-B-fragment-linear layout: 32 frags f = n*4+ks, 64 lanes x 16B; lane l
// of frag f holds W[n*16+(l&15)][ks*32+(l>>4)*8 + j], j=0..7.
// ---------------------------------------------------------------------------
__global__ __launch_bounds__(256) void binscatter_k(
    const int* __restrict__ eidx, unsigned* __restrict__ count,
    unsigned* __restrict__ payload, const float* __restrict__ W,
    unsigned* __restrict__ Wbf)
{
    if (blockIdx.x == EBLK) {
        int t = threadIdx.x;
        #pragma unroll
        for (int i = 0; i < 8; ++i) {
            int u = t * 8 + i;          // 16B unit index, 0..2047
            int l = u & 63, f = u >> 6; // f = n*4 + ks
            int c16 = l & 15, q = l >> 4;
            int col = (f >> 2) * 16 + c16;
            int kb  = (f & 3) * 32 + q * 8;
            const float* wp = W + col * CDIM + kb;
            float4 w0 = *reinterpret_cast<const float4*>(wp);
            float4 w1 = *reinterpret_cast<const float4*>(wp + 4);
            uint4 pk;
            pk.x = (unsigned)f2bf(w0.x) | ((unsigned)f2bf(w0.y) << 16);
            pk.y = (unsigned)f2bf(w0.z) | ((unsigned)f2bf(w0.w) << 16);
            pk.z = (unsigned)f2bf(w1.x) | ((unsigned)f2bf(w1.y) << 16);
            pk.w = (unsigned)f2bf(w1.z) | ((unsigned)f2bf(w1.w) << 16);
            reinterpret_cast<uint4*>(Wbf)[u] = pk;
        }
        return;
    }
    int e = blockIdx.x * 256 + threadIdx.x;
    if (e >= EE) return;
    int b = eidx[e];
    int t = eidx[EE + e];
    int s = eidx[2 * EE + e];
    int r = eidx[3 * EE + e];
    int seg = b * NN + t;
    unsigned slot = atomicAdd(count + seg, 1u);
    if (slot < CAP) payload[(size_t)seg * CAP + slot] = (unsigned)s | ((unsigned)r << 16);
}

// ---------------------------------------------------------------------------
// fused_k: 512 threads = 8 waves; block owns 16 segments (one 16x128 tile).
// Wave w: B-frags for cols w*16..w*16+15 PREFETCHED to VGPRs from global
// Wbf (L2-hot, consumed only after the barrier -> free prefetch; no W LDS,
// no staging conflicts). rel (32 KB f32) staged linearly into LDS once.
// Gather: wave w owns segments blk*16 + w*2, +1. Lane (q=l>>4, c=l&15):
// quarter q processes edges q, q+4, ...; 8 edges in flight per chunk; node
// rows from global (float4 x2/lane), rel rows from LDS. Clamped indices +
// 0/1 weights keep loads branchless. Combine via shfl_xor(16/32); mean
// fused; row -> Xl as bf16, XOR-swizzled.
// MFMA: A-frags from Xl; wave w computes its 16 cols (4 MFMAs).
// ---------------------------------------------------------------------------
__global__ __launch_bounds__(512) void fused_k(
    const float* __restrict__ node, const float* __restrict__ rel,
    const unsigned* __restrict__ count, const unsigned* __restrict__ payload,
    const unsigned* __restrict__ Wbf, float* __restrict__ out)
{
    __shared__ __align__(16) float Rl[64 * CDIM];           // 32 KB rel f32
    __shared__ __align__(16) unsigned short Xl[16 * CDIM];  // 4 KB swizzled

    const int tid = threadIdx.x;
    const int wav = tid >> 6;
    const int l   = tid & 63;
    const int q   = l >> 4;
    const int c   = l & 15;

    // prefetch this wave's 4 B-fragments (consumed after the barrier)
    bf16x8 bfr[4];
    #pragma unroll
    for (int ks = 0; ks < 4; ++ks)
        bfr[ks] = reinterpret_cast<const bf16x8*>(Wbf)[(wav * 4 + ks) * 64 + l];

    // stage rel -> LDS, linear (conflict-free): 2048 float4, 512 thr x 4
    {
        const float4* src = reinterpret_cast<const float4*>(rel);
        float4* dst = reinterpret_cast<float4*>(Rl);
        #pragma unroll
        for (int i = 0; i < 4; ++i) dst[i * 512 + tid] = src[i * 512 + tid];
    }

    const int seg0 = blockIdx.x * 16 + wav * 2;
    const uint2 c2 = *reinterpret_cast<const uint2*>(count + seg0);  // broadcast
    unsigned pv0 = payload[(size_t)seg0 * CAP + (l & 31)];
    unsigned pv1 = payload[(size_t)(seg0 + 1) * CAP + (l & 31)];

    __syncthreads();  // Rl ready

    #pragma unroll
    for (int si = 0; si < 2; ++si) {
        int seg = seg0 + si;
        unsigned cnt = si ? c2.y : c2.x;
        if (cnt > CAP) cnt = CAP;
        unsigned pv = si ? pv1 : pv0;
        int b = (seg >= NN) ? 1 : 0;

        const float* nb = node + (size_t)b * NN * CDIM + c * 8;
        const float* rb = Rl + c * 8;

        float acc[8];
        #pragma unroll
        for (int i = 0; i < 8; ++i) acc[i] = 0.f;

        for (unsigned base = 0; base < cnt; base += 8) {
            unsigned j0 = base + q, j1 = base + 4 + q;
            unsigned jc0 = (j0 < cnt) ? j0 : (cnt - 1);
            unsigned jc1 = (j1 < cnt) ? j1 : (cnt - 1);
            float w0 = (j0 < cnt) ? 1.f : 0.f;
            float w1 = (j1 < cnt) ? 1.f : 0.f;
            unsigned p0 = __shfl(pv, (int)jc0, 32);
            unsigned p1 = __shfl(pv, (int)jc1, 32);
            int s0 = (int)(p0 & 0xFFFFu), r0 = (int)(p0 >> 16);
            int s1 = (int)(p1 & 0xFFFFu), r1 = (int)(p1 >> 16);
            const float* h0 = nb + (size_t)s0 * CDIM;
            const float* h1 = nb + (size_t)s1 * CDIM;
            float4 h0a = *reinterpret_cast<const float4*>(h0);
            float4 h0b = *reinterpret_cast<const float4*>(h0 + 4);
            float4 h1a = *reinterpret_cast<const float4*>(h1);
            float4 h1b = *reinterpret_cast<const float4*>(h1 + 4);
            float4 r0a = *reinterpret_cast<const float4*>(rb + r0 * CDIM);
            float4 r0b = *reinterpret_cast<const float4*>(rb + r0 * CDIM + 4);
            float4 r1a = *reinterpret_cast<const float4*>(rb + r1 * CDIM);
            float4 r1b = *reinterpret_cast<const float4*>(rb + r1 * CDIM + 4);
            acc[0] = fmaf(w0, h0a.x - r0a.x, acc[0]);
            acc[1] = fmaf(w0, h0a.y - r0a.y, acc[1]);
            acc[2] = fmaf(w0, h0a.z - r0a.z, acc[2]);
            acc[3] = fmaf(w0, h0a.w - r0a.w, acc[3]);
            acc[4] = fmaf(w0, h0b.x - r0b.x, acc[4]);
            acc[5] = fmaf(w0, h0b.y - r0b.y, acc[5]);
            acc[6] = fmaf(w0, h0b.z - r0b.z, acc[6]);
            acc[7] = fmaf(w0, h0b.w - r0b.w, acc[7]);
            acc[0] = fmaf(w1, h1a.x - r1a.x, acc[0]);
            acc[1] = fmaf(w1, h1a.y - r1a.y, acc[1]);
            acc[2] = fmaf(w1, h1a.z - r1a.z, acc[2]);
            acc[3] = fmaf(w1, h1a.w - r1a.w, acc[3]);
            acc[4] = fmaf(w1, h1b.x - r1b.x, acc[4]);
            acc[5] = fmaf(w1, h1b.y - r1b.y, acc[5]);
            acc[6] = fmaf(w1, h1b.z - r1b.z, acc[6]);
            acc[7] = fmaf(w1, h1b.w - r1b.w, acc[7]);
        }

        // combine quarters: all lanes end with the full 128-dim sum
        #pragma unroll
        for (int i = 0; i < 8; ++i) {
            acc[i] += __shfl_xor(acc[i], 16);
            acc[i] += __shfl_xor(acc[i], 32);
        }

        if (q == 0) {
            float inv = 1.f / (float)cnt;  // cnt >= 1 (cover edges)
            int row = wav * 2 + si;
            uint4 pk;
            pk.x = (unsigned)f2bf(acc[0] * inv) | ((unsigned)f2bf(acc[1] * inv) << 16);
            pk.y = (unsigned)f2bf(acc[2] * inv) | ((unsigned)f2bf(acc[3] * inv) << 16);
            pk.z = (unsigned)f2bf(acc[4] * inv) | ((unsigned)f2bf(acc[5] * inv) << 16);
            pk.w = (unsigned)f2bf(acc[6] * inv) | ((unsigned)f2bf(acc[7] * inv) << 16);
            int off = (row * 256 + c * 16) ^ ((row & 7) << 4);
            *reinterpret_cast<uint4*>((char*)Xl + off) = pk;
        }
    }

    __syncthreads();  // x-tile staged

    // A-frags: lane row = c, k = ks*32 + q*8 + j
    bf16x8 afr[4];
    #pragma unroll
    for (int ks = 0; ks < 4; ++ks) {
        int off = (c * 256 + ks * 64 + q * 16) ^ ((c & 7) << 4);
        afr[ks] = *reinterpret_cast<const bf16x8*>((const char*)Xl + off);
    }

    f32x4 accv = (f32x4){0.f, 0.f, 0.f, 0.f};
    #pragma unroll
    for (int ks = 0; ks < 4; ++ks)
        accv = __builtin_amdgcn_mfma_f32_16x16x32_bf16(afr[ks], bfr[ks], accv, 0, 0, 0);

    // store: row = blk*16 + q*4 + j, col = wav*16 + c  [C/D: col=l&15, row=(l>>4)*4+reg]
    size_t rowbase = (size_t)blockIdx.x * 16;
    #pragma unroll
    for (int j = 0; j < 4; ++j)
        out[(rowbase + q * 4 + j) * CDIM + wav * 16 + c] = accv[j];
}

extern "C" void kernel_launch(void* const* d_in, const int* in_sizes, int n_in,
                              void* d_out, int out_size, void* d_ws, size_t ws_size,
                              hipStream_t stream) {
    const float* node = (const float*)d_in[0];
    const int*   eidx = (const int*)d_in[1];
    const float* rel  = (const float*)d_in[2];
    const float* W    = (const float*)d_in[3];
    float* out = (float*)d_out;

    // ws: count u32[SEGS] @0 (400000 B); payload u32[SEGS*CAP] @400000 (12.8 MB);
    //     Wbf (32 KB bf16 frag-linear) @13200000
    unsigned* count   = (unsigned*)d_ws;
    unsigned* payload = (unsigned*)((char*)d_ws + 400000);
    unsigned* Wbf     = (unsigned*)((char*)d_ws + 13200000);

    hipMemsetAsync(count, 0, (size_t)SEGS * sizeof(unsigned), stream);

    binscatter_k<<<EBLK + 1, 256, 0, stream>>>(eidx, count, payload, W, Wbf);
    fused_k<<<SEGS / 16, 512, 0, stream>>>(node, rel, count, payload, Wbf, out);
}